// Round 8
// baseline (172.999 us; speedup 1.0000x reference)
//
#include <hip/hip_runtime.h>

// Attention forward, bf16-MFMA end-to-end. B=2, N=2048, C=1024, H=16, Dh=64.
// R14: attn cross-tile software pipeline. R13 was overlap-bound (2 waves/SIMD
// in barrier lockstep: MFMA and VALU phases alternate idle; 3400cy/tile vs
// ~1800cy max-pipe floor). Each wave now interleaves exp/pack+PV of tile t
// with QK of tile t+1 (independent work -> single-wave MFMA/VALU overlap).
// K double-buffered, V quad-buffered (48KB LDS) so STAGE(t+2) never clobbers
// the V tile PV(t) reads; one vmcnt(0)+s_barrier per tile; x2-unrolled loop
// keeps all register state (sA/sB) statically indexed. Math is a pure reorder
// (no max-tracking; k-sum commutes). gemm/prep unchanged from R12 (controls).

typedef short v8s __attribute__((ext_vector_type(8)));
typedef float v4f __attribute__((ext_vector_type(4)));
typedef unsigned int v4u __attribute__((ext_vector_type(4)));

#define QSCALE 0.18033688011112042f   // 0.125 * log2(e): softmax runs in exp2 domain

// bare-metal 2^x: v_exp_f32 (exact instruction; scores are bounded, no fixup needed)
#if defined(__has_builtin)
# if __has_builtin(__builtin_amdgcn_exp2f)
#  define EXP2(x) __builtin_amdgcn_exp2f(x)
# endif
#endif
#ifndef EXP2
static __device__ __forceinline__ float exp2_asm(float x) {
    float r;
    asm volatile("v_exp_f32 %0, %1\n\ts_nop 1" : "=v"(r) : "v"(x));
    return r;
}
# define EXP2(x) exp2_asm(x)
#endif

static __device__ __forceinline__ unsigned short f2bf_fast(float f) {
    union { float f; unsigned int u; } a;
    a.f = f;
    return (unsigned short)((a.u + 0x8000u) >> 16);   // half-up ~= RNE
}

// pack two f32 -> bf16x2 (lo | hi<<16): 2 adds + 1 v_perm
static __device__ __forceinline__ unsigned int pack_bf16(float lo, float hi) {
    union { float f; unsigned int u; } a, b;
    a.f = lo; b.f = hi;
    return __builtin_amdgcn_perm(b.u + 0x8000u, a.u + 0x8000u, 0x07060302u);
}

#define GLD16(g, l) __builtin_amdgcn_global_load_lds( \
    (const __attribute__((address_space(1))) unsigned int*)(g), \
    (__attribute__((address_space(3))) unsigned int*)(l), 16, 0, 0)

// ---------------- fused prep: x cvt + w_qkv/w_proj transpose-convert ----------------
// grid 8192x256: blocks [0,4096) cvt x; [4096,7168) transp w_qkv; [7168,8192) w_proj.
__global__ __launch_bounds__(256) void prep(const float* __restrict__ x,
                                            unsigned short* __restrict__ xb,
                                            const float* __restrict__ w_qkv,
                                            unsigned short* __restrict__ wqkvt,
                                            const float* __restrict__ w_proj,
                                            unsigned short* __restrict__ wprojt) {
    __shared__ float tile[32][33];
    const int bid = blockIdx.x, tid = threadIdx.x;
    if (bid < 4096) {
        int i = bid * 256 + tid;
        float4 f = ((const float4*)x)[i];
        ushort4 o;
        o.x = f2bf_fast(f.x); o.y = f2bf_fast(f.y); o.z = f2bf_fast(f.z); o.w = f2bf_fast(f.w);
        ((ushort4*)xb)[i] = o;
        return;
    }
    const float* w; unsigned short* wt; int R, C, bx, by;
    if (bid < 7168) { w = w_qkv; wt = wqkvt; R = 1024; C = 3072;
                      int t = bid - 4096; bx = t % 96; by = t / 96; }
    else            { w = w_proj; wt = wprojt; R = 1024; C = 1024;
                      int t = bid - 7168; bx = t & 31; by = t >> 5; }
    const int tx = tid & 31, ty = tid >> 5;       // (32, 8)
    const int c0 = bx * 32, r0 = by * 32;
#pragma unroll
    for (int j = 0; j < 32; j += 8)
        tile[ty + j][tx] = w[(r0 + ty + j) * C + c0 + tx];
    __syncthreads();
#pragma unroll
    for (int j = 0; j < 32; j += 8)
        wt[(c0 + ty + j) * R + r0 + tx] = f2bf_fast(tile[tx][ty + j]);
}

// ---------------- bf16 GEMM 128x128: A[M][K] @ Bt[N][K]^T + bias ----------------
// BK=32, 3 rotating LDS buffers, depth-2 prefetch, raw s_barrier + counted
// vmcnt(4) (one barrier per K-step; loads never drain to 0 in the loop).
// Staging slot (r, j) holds global chunk j ^ ((r>>1)&3); readers use chunk
// quad ^ ((l16>>1)&3) -> conflict-free. XCD-aware block swizzle (bijective,
// grid %8 == 0). mode 0: q (prescaled QSCALE) / k [bh][n][64] via LDS-dense
// 16B stores; vt [bh][64][n'] via LDS transpose (n' = sigma order). mode 1: fp32.
__global__ __launch_bounds__(256) void gemm_bt(const unsigned short* __restrict__ A,
                                               const unsigned short* __restrict__ Bt,
                                               const float* __restrict__ bias,
                                               int M, int N, int K, int mode,
                                               unsigned short* __restrict__ qo,
                                               unsigned short* __restrict__ ko,
                                               unsigned short* __restrict__ vto,
                                               float* __restrict__ outp) {
    // staging: 3 buffers x (A 4096 + B 4096) ushorts = 49152 B;
    // epilogues reuse [0,17408) ushorts as a 128x136 tile buffer.
    __shared__ unsigned short Sh[24576];
    const int tid = threadIdx.x;
    const int wave = tid >> 6, lane = tid & 63;
    const int quad = lane >> 4, l16 = lane & 15;
    // XCD-aware bijective swizzle: nwg = W*32 (768 or 256), both %8 == 0.
    const int W = gridDim.x;
    const int id = blockIdx.y * W + blockIdx.x;
    const int s = (id & 7) * (W << 2) + (id >> 3);
    const int bm = (s / W) * 128, bn = (s % W) * 128;
    const int wm = (wave >> 1) * 64, wn = (wave & 1) * 64;
    const int rsw = (quad ^ ((l16 >> 1) & 3)) << 3;   // reader chunk offset (ushorts)

    v4f acc[4][4];
#pragma unroll
    for (int i = 0; i < 4; i++)
#pragma unroll
        for (int j = 0; j < 4; j++) acc[i][j] = (v4f){0.f, 0.f, 0.f, 0.f};

#define GSTAGE(off, kk) do { \
    _Pragma("unroll") \
    for (int i_ = 0; i_ < 2; i_++) { \
        int c_ = i_ * 256 + tid; \
        int r_ = c_ >> 2; \
        int g_ = ((c_ & 3) ^ ((r_ >> 1) & 3)) << 3; \
        GLD16(&A[(bm + r_) * K + (kk) + g_], &Sh[(off) + (c_ << 3)]); \
        GLD16(&Bt[(bn + r_) * K + (kk) + g_], &Sh[(off) + 4096 + (c_ << 3)]); \
    } } while (0)

#define GCOMP(off) do { \
    v8s af_[4], bf_[4]; \
    _Pragma("unroll") \
    for (int mi_ = 0; mi_ < 4; mi_++) \
        af_[mi_] = *(const v8s*)&Sh[(off) + (wm + mi_ * 16 + l16) * 32 + rsw]; \
    _Pragma("unroll") \
    for (int ni_ = 0; ni_ < 4; ni_++) \
        bf_[ni_] = *(const v8s*)&Sh[(off) + 4096 + (wn + ni_ * 16 + l16) * 32 + rsw]; \
    _Pragma("unroll") \
    for (int mi_ = 0; mi_ < 4; mi_++) \
        _Pragma("unroll") \
        for (int ni_ = 0; ni_ < 4; ni_++) \
            acc[mi_][ni_] = __builtin_amdgcn_mfma_f32_16x16x32_bf16( \
                af_[mi_], bf_[ni_], acc[mi_][ni_], 0, 0, 0); \
    } while (0)

    const int nt = K >> 5;                 // K/32 steps (32 for K=1024)
    int o0 = 0, o1 = 8192, o2 = 16384;     // rotating buffer offsets (ushorts)
    GSTAGE(o0, 0);
    GSTAGE(o1, 32);
    for (int t = 0; t < nt - 1; ++t) {
        // retire buf[t]'s 4 loads; buf[t+1]'s 4 stay in flight across the barrier
        asm volatile("s_waitcnt vmcnt(4)" ::: "memory");
        __builtin_amdgcn_s_barrier();
        __builtin_amdgcn_sched_barrier(0);
        if (t + 2 < nt) GSTAGE(o2, (t + 2) << 5);
        GCOMP(o0);
        int tmp = o0; o0 = o1; o1 = o2; o2 = tmp;
    }
    asm volatile("s_waitcnt vmcnt(0)" ::: "memory");
    __builtin_amdgcn_s_barrier();
    __builtin_amdgcn_sched_barrier(0);
    GCOMP(o0);
#undef GSTAGE
#undef GCOMP

    if (mode == 1) {
#pragma unroll
        for (int mi = 0; mi < 4; mi++)
#pragma unroll
            for (int ni = 0; ni < 4; ni++) {
                int col = bn + wn + ni * 16 + l16;
                float bv = bias[col];
                int row0 = bm + wm + mi * 16 + quad * 4;
#pragma unroll
                for (int r = 0; r < 4; r++)
                    outp[(row0 + r) * N + col] = acc[mi][ni][r] + bv;
            }
    } else if (bn < 2048) {
        // q or k: acc -> Sh row-major [r][c] pad 136 -> dense 16B row stores
        const int isq = (bn < 1024);
        unsigned short* dst = isq ? qo : ko;
        const float sc = isq ? QSCALE : 1.0f;
        __syncthreads();                          // staging reads done; Sh reusable
#pragma unroll
        for (int mi = 0; mi < 4; mi++)
#pragma unroll
            for (int ni = 0; ni < 4; ni++) {
                int c = wn + ni * 16 + l16;
                float bv = bias[bn + c];
                int r0 = wm + mi * 16 + quad * 4;
#pragma unroll
                for (int r = 0; r < 4; r++)
                    Sh[(r0 + r) * 136 + c] = f2bf_fast((acc[mi][ni][r] + bv) * sc);
            }
        __syncthreads();
        const int bb = bm >> 11, nb = bm & 2047;
#pragma unroll
        for (int j = 0; j < 8; j++) {
            int idx = j * 256 + tid;              // 2048 chunks: row=idx>>4, c8=idx&15
            int r = idx >> 4, c8 = idx & 15;
            int rem = (bn + c8 * 8) & 1023;
            int h = rem >> 6, dh = rem & 63;
            *(int4*)&dst[(((bb * 16 + h) << 11) + nb + r) * 64 + dh] =
                *(const int4*)&Sh[r * 136 + c8 * 8];
        }
    } else {
        // vt: transpose through LDS -> dense 16B stores. Sh[col_local*136 + row_local']
        // row_local' applies sigma within the wave's 64-key tile: each ushort4 pk is
        // one (m=mi, q=quad) group of 4 keys -> slot base 32*(mi>>1)+8*quad+4*(mi&1).
        __syncthreads();                          // staging reads done; Sh reusable
#pragma unroll
        for (int mi = 0; mi < 4; mi++)
#pragma unroll
            for (int ni = 0; ni < 4; ni++) {
                int col = bn + wn + ni * 16 + l16;
                float bv = bias[col];
                ushort4 pk;
                pk.x = f2bf_fast(acc[mi][ni][0] + bv);
                pk.y = f2bf_fast(acc[mi][ni][1] + bv);
                pk.z = f2bf_fast(acc[mi][ni][2] + bv);
                pk.w = f2bf_fast(acc[mi][ni][3] + bv);
                *(ushort4*)&Sh[(wn + ni * 16 + l16) * 136 +
                               wm + ((mi >> 1) * 32) + quad * 8 + ((mi & 1) * 4)] = pk;
            }
        __syncthreads();
        const int b = bm >> 11, n_base = bm & 2047;
#pragma unroll
        for (int j = 0; j < 8; j++) {
            int idx = j * 256 + tid;           // 2048 chunks of 8 ushorts
            int Lcol = idx >> 4, rc = idx & 15;
            int rem = (bn + Lcol) & 1023;
            int h = rem >> 6, dh = rem & 63;
            *(int4*)&vto[((((b * 16 + h) * 64 + dh) << 11) + n_base + rc * 8)] =
                *(const int4*)&Sh[Lcol * 136 + rc * 8];
        }
    }
}

// ---------------- flash attention: BK=64, 32 q-rows/wave, pipelined ----------------
// q (prescaled), k: [bh][2048][64]; vt: [bh][64][2048 sigma-slots]; o: bf16
// Per tile phase (between barriers): EXPP(s_prev)->af [VALU] || QK(K[cur]) ->
// s_cur [MFMA on fresh LDS] || PV(af, V[prev]) [MFMA] -- independent chains the
// scheduler interleaves. K[2], V[4] buffers; STAGE(t+2) issued at phase bottom
// (covered by a full tile of compute); vmcnt(0)+s_barrier per phase.
__global__ __launch_bounds__(256, 2) void attn(const unsigned short* __restrict__ q,
                                               const unsigned short* __restrict__ k,
                                               const unsigned short* __restrict__ vt,
                                               unsigned short* __restrict__ o) {
    __shared__ unsigned short KsF[2 * 4096];    // [key][d]   swizzled  (2 x 8192 B)
    __shared__ unsigned short VsF[4 * 4096];    // [d][slot]  swizzled  (4 x 8192 B)
    const int tid = threadIdx.x;
    const int wave = tid >> 6, lane = tid & 63;
    const int quad = lane >> 4, l16 = lane & 15;
    const int sw = l16 & 7;

    // XCD-aware swizzle: id in [0,512). Low 5 bits -> bh (8 XCDs x 4 bh each),
    // high bits -> q-block in [0,16). Each XCD sees 4 bh => K/V fits its L2.
    const int id = blockIdx.y * 16 + blockIdx.x;
    const int bh = (id & 7) * 4 + ((id >> 3) & 3);
    const int wq0 = (id >> 5) * 128 + wave * 32;
    const int rowg = bh * 2048 + wq0;

    // Q B-frags: group g covers q-rows wq0 + g*16 + l16, d = half*32 + quad*8..+7
    v8s qf[2][2];
#pragma unroll
    for (int g = 0; g < 2; g++)
#pragma unroll
        for (int half = 0; half < 2; half++)
            qf[g][half] = *(const v8s*)&q[(rowg + g * 16 + l16) * 64 + half * 32 + quad * 8];

    // register ones B-frag (bf16 1.0)
    v8s onef;
#pragma unroll
    for (int j = 0; j < 8; j++) onef[j] = (short)0x3F80;

    v4f oacc[2][4];
    v4f lacc[2];
#pragma unroll
    for (int g = 0; g < 2; g++) {
        lacc[g] = (v4f){0.f, 0.f, 0.f, 0.f};
#pragma unroll
        for (int dt = 0; dt < 4; dt++) oacc[g][dt] = (v4f){0.f, 0.f, 0.f, 0.f};
    }

    const unsigned short* kbase = k + (((long)bh << 11) * 64);
    const unsigned short* vbase = vt + (((long)bh * 64) << 11);

#define STAGE(ko, vo, n0s) do { \
    _Pragma("unroll") \
    for (int i_ = 0; i_ < 2; i_++) { \
        int c_ = i_ * 256 + tid; \
        int r_ = c_ >> 3; \
        int chs_ = ((c_ & 7) ^ (r_ & 7)) << 3; \
        GLD16(&kbase[((n0s) + r_) * 64 + chs_], &KsF[(ko) + (c_ << 3)]); \
        GLD16(&vbase[(r_ << 11) + (n0s) + chs_], &VsF[(vo) + (c_ << 3)]); \
    } } while (0)

#define WAITB() do { asm volatile("s_waitcnt vmcnt(0)" ::: "memory"); \
    __builtin_amdgcn_s_barrier(); __builtin_amdgcn_sched_barrier(0); } while (0)

    // QK: S^T for both q-groups; s[g][ni][r] = S[key=ni*16+quad*4+r][wq0+g*16+l16]
    auto QK = [&](const unsigned short* Kc, v4f (&sreg)[2][4]) {
#pragma unroll
        for (int ni = 0; ni < 4; ni++) {
            int rowk = (ni * 16 + l16) * 64;
            v8s kf0 = *(const v8s*)&Kc[rowk + ((quad ^ sw) << 3)];
            v8s kf1 = *(const v8s*)&Kc[rowk + (((4 + quad) ^ sw) << 3)];
#pragma unroll
            for (int g = 0; g < 2; g++) {
                v4f z = (v4f){0.f, 0.f, 0.f, 0.f};
                z = __builtin_amdgcn_mfma_f32_16x16x32_bf16(kf0, qf[g][0], z, 0, 0, 0);
                z = __builtin_amdgcn_mfma_f32_16x16x32_bf16(kf1, qf[g][1], z, 0, 0, 0);
                sreg[g][ni] = z;
            }
        }
    };
    // EXPP: exp2 + in-register kappa pack -> A-frags
    auto EXPP = [&](v4f (&sreg)[2][4], v8s (&af)[2][2]) {
#pragma unroll
        for (int g = 0; g < 2; g++)
#pragma unroll
            for (int t = 0; t < 2; t++) {
                v4u w;
                w[0] = pack_bf16(EXP2(sreg[g][2 * t][0]),     EXP2(sreg[g][2 * t][1]));
                w[1] = pack_bf16(EXP2(sreg[g][2 * t][2]),     EXP2(sreg[g][2 * t][3]));
                w[2] = pack_bf16(EXP2(sreg[g][2 * t + 1][0]), EXP2(sreg[g][2 * t + 1][1]));
                w[3] = pack_bf16(EXP2(sreg[g][2 * t + 1][2]), EXP2(sreg[g][2 * t + 1][3]));
                union { v4u u; v8s s8; } cv;
                cv.u = w;
                af[g][t] = cv.s8;
            }
    };
    // PV: O += P V (sigma-slotted V: one b128/frag, conflict-free); l += P.1
    auto PV = [&](v8s (&af)[2][2], const unsigned short* Vc) {
#pragma unroll
        for (int dt = 0; dt < 4; dt++) {
            int rowv = (dt * 16 + l16) * 64;
            v8s vf0 = *(const v8s*)&Vc[rowv + ((quad ^ sw) << 3)];
            v8s vf1 = *(const v8s*)&Vc[rowv + (((4 + quad) ^ sw) << 3)];
#pragma unroll
            for (int g = 0; g < 2; g++) {
                oacc[g][dt] = __builtin_amdgcn_mfma_f32_16x16x32_bf16(af[g][0], vf0, oacc[g][dt], 0, 0, 0);
                oacc[g][dt] = __builtin_amdgcn_mfma_f32_16x16x32_bf16(af[g][1], vf1, oacc[g][dt], 0, 0, 0);
            }
        }
#pragma unroll
        for (int g = 0; g < 2; g++) {
            lacc[g] = __builtin_amdgcn_mfma_f32_16x16x32_bf16(af[g][0], onef, lacc[g], 0, 0, 0);
            lacc[g] = __builtin_amdgcn_mfma_f32_16x16x32_bf16(af[g][1], onef, lacc[g], 0, 0, 0);
        }
    };

    v4f sA[2][4], sB[2][4];
    v8s afA[2][2], afB[2][2];

    // prologue: tile0 -> K0/V0; QK(0); stage tile1 -> K1/V1
    STAGE(0, 0, 0);
    WAITB();
    QK(KsF, sA);
    STAGE(4096, 4096, 64);

    // main: 15 x2 bodies, i = 1,3,...,29. Body A: finish tile i-1, QK tile i (K1),
    // stage tile i+1. Body B: finish tile i, QK tile i+1 (K0), stage tile i+2.
    for (int i = 1; i < 31; i += 2) {
        WAITB();                                   // K/V of tile i staged
        __builtin_amdgcn_s_setprio(1);
        EXPP(sA, afA);
        QK(KsF + 4096, sB);
        PV(afA, VsF + (((i - 1) & 3) << 12));
        __builtin_amdgcn_s_setprio(0);
        STAGE(0, ((i + 1) & 3) << 12, (i + 1) * 64);

        WAITB();                                   // K/V of tile i+1 staged
        __builtin_amdgcn_s_setprio(1);
        EXPP(sB, afB);
        QK(KsF, sA);
        PV(afB, VsF + ((i & 3) << 12));
        __builtin_amdgcn_s_setprio(0);
        STAGE(4096, ((i + 2) & 3) << 12, (i + 2) * 64);
    }

    // epilogue: tile 31 staged by last body. Finish tile 30, QK+finish tile 31.
    WAITB();
    __builtin_amdgcn_s_setprio(1);
    EXPP(sA, afA);
    QK(KsF + 4096, sB);
    PV(afA, VsF + ((30 & 3) << 12));
    EXPP(sB, afB);
    PV(afB, VsF + ((31 & 3) << 12));
    __builtin_amdgcn_s_setprio(0);
#undef STAGE
#undef WAITB

    const int b = bh >> 4, h = bh & 15;
#pragma unroll
    for (int g = 0; g < 2; g++)
#pragma unroll
        for (int r = 0; r < 4; r++) {
            float linv = 1.0f / lacc[g][r];   // l present in every lane (broadcast ones B)
            int n = wq0 + g * 16 + quad * 4 + r;
#pragma unroll
            for (int dt = 0; dt < 4; dt++)
                o[(b * 2048 + n) * 1024 + h * 64 + dt * 16 + l16] =
                    f2bf_fast(oacc[g][dt][r] * linv);
        }
}

extern "C" void kernel_launch(void* const* d_in, const int* in_sizes, int n_in,
                              void* d_out, int out_size, void* d_ws, size_t ws_size,
                              hipStream_t stream) {
    const float* x      = (const float*)d_in[0];   // [2,2048,1024]
    const float* w_qkv  = (const float*)d_in[1];   // [1024,3072]
    const float* b_qkv  = (const float*)d_in[2];   // [3072]
    const float* w_proj = (const float*)d_in[3];   // [1024,1024]
    const float* b_proj = (const float*)d_in[4];   // [1024]
    float* outp = (float*)d_out;                   // [2,2048,1024] fp32

    unsigned short* ws     = (unsigned short*)d_ws;
    unsigned short* xb     = ws;                   // 4096*1024
    unsigned short* wqkvt  = ws + 4194304;         // 3072*1024
    unsigned short* wprojt = wqkvt + 3145728;      // 1024*1024
    unsigned short* qws    = wprojt + 1048576;     // 32*2048*64
    unsigned short* kws    = qws + 4194304;
    unsigned short* vtws   = kws + 4194304;
    unsigned short* ows    = xb;                   // alias: xb dead after QKV GEMM

    prep<<<8192, 256, 0, stream>>>(x, xb, w_qkv, wqkvt, w_proj, wprojt);
    gemm_bt<<<dim3(24, 32), 256, 0, stream>>>(xb, wqkvt, b_qkv, 4096, 3072, 1024, 0,
                                              qws, kws, vtws, nullptr);
    attn<<<dim3(16, 32), 256, 0, stream>>>(qws, kws, vtws, ows);
    gemm_bt<<<dim3(8, 32), 256, 0, stream>>>(ows, wprojt, b_proj, 4096, 1024, 1024, 1,
                                             nullptr, nullptr, nullptr, outp);
}

// Round 9
// 166.748 us; speedup vs baseline: 1.0375x; 1.0375x over previous
//
#include <hip/hip_runtime.h>

// Attention forward, bf16-MFMA end-to-end. B=2, N=2048, C=1024, H=16, Dh=64.
// R15: fix R14's staging-exposure bug + kill runtime addressing.
// (1) attn STAGE moved to TOP of each phase (right after vmcnt(0)+barrier):
//     stage(t+1) now has a full phase of EXPP/QK/PV to cover its latency; R14
//     issued it at phase bottom, immediately before the next drain -> full
//     latency exposed every tile. (2) attn 32 phases FULLY UNROLLED (PHASE(T)
//     macro, T literal): K/V buffer offsets and stage addresses all
//     compile-time static. (3) gemm K-loop triple-unrolled: 3-buffer rotation
//     static (was runtime o0/o1/o2 swap). Cross-tile interleave, sigma-slotted
//     V, kappa-packed P, counted vmcnt in gemm all carried forward.

typedef short v8s __attribute__((ext_vector_type(8)));
typedef float v4f __attribute__((ext_vector_type(4)));
typedef unsigned int v4u __attribute__((ext_vector_type(4)));

#define QSCALE 0.18033688011112042f   // 0.125 * log2(e): softmax runs in exp2 domain

// bare-metal 2^x: v_exp_f32 (exact instruction; scores are bounded, no fixup needed)
#if defined(__has_builtin)
# if __has_builtin(__builtin_amdgcn_exp2f)
#  define EXP2(x) __builtin_amdgcn_exp2f(x)
# endif
#endif
#ifndef EXP2
static __device__ __forceinline__ float exp2_asm(float x) {
    float r;
    asm volatile("v_exp_f32 %0, %1\n\ts_nop 1" : "=v"(r) : "v"(x));
    return r;
}
# define EXP2(x) exp2_asm(x)
#endif

static __device__ __forceinline__ unsigned short f2bf_fast(float f) {
    union { float f; unsigned int u; } a;
    a.f = f;
    return (unsigned short)((a.u + 0x8000u) >> 16);   // half-up ~= RNE
}

// pack two f32 -> bf16x2 (lo | hi<<16): 2 adds + 1 v_perm
static __device__ __forceinline__ unsigned int pack_bf16(float lo, float hi) {
    union { float f; unsigned int u; } a, b;
    a.f = lo; b.f = hi;
    return __builtin_amdgcn_perm(b.u + 0x8000u, a.u + 0x8000u, 0x07060302u);
}

#define GLD16(g, l) __builtin_amdgcn_global_load_lds( \
    (const __attribute__((address_space(1))) unsigned int*)(g), \
    (__attribute__((address_space(3))) unsigned int*)(l), 16, 0, 0)

// ---------------- fused prep: x cvt + w_qkv/w_proj transpose-convert ----------------
// grid 8192x256: blocks [0,4096) cvt x; [4096,7168) transp w_qkv; [7168,8192) w_proj.
__global__ __launch_bounds__(256) void prep(const float* __restrict__ x,
                                            unsigned short* __restrict__ xb,
                                            const float* __restrict__ w_qkv,
                                            unsigned short* __restrict__ wqkvt,
                                            const float* __restrict__ w_proj,
                                            unsigned short* __restrict__ wprojt) {
    __shared__ float tile[32][33];
    const int bid = blockIdx.x, tid = threadIdx.x;
    if (bid < 4096) {
        int i = bid * 256 + tid;
        float4 f = ((const float4*)x)[i];
        ushort4 o;
        o.x = f2bf_fast(f.x); o.y = f2bf_fast(f.y); o.z = f2bf_fast(f.z); o.w = f2bf_fast(f.w);
        ((ushort4*)xb)[i] = o;
        return;
    }
    const float* w; unsigned short* wt; int R, C, bx, by;
    if (bid < 7168) { w = w_qkv; wt = wqkvt; R = 1024; C = 3072;
                      int t = bid - 4096; bx = t % 96; by = t / 96; }
    else            { w = w_proj; wt = wprojt; R = 1024; C = 1024;
                      int t = bid - 7168; bx = t & 31; by = t >> 5; }
    const int tx = tid & 31, ty = tid >> 5;       // (32, 8)
    const int c0 = bx * 32, r0 = by * 32;
#pragma unroll
    for (int j = 0; j < 32; j += 8)
        tile[ty + j][tx] = w[(r0 + ty + j) * C + c0 + tx];
    __syncthreads();
#pragma unroll
    for (int j = 0; j < 32; j += 8)
        wt[(c0 + ty + j) * R + r0 + tx] = f2bf_fast(tile[tx][ty + j]);
}

// ---------------- bf16 GEMM 128x128: A[M][K] @ Bt[N][K]^T + bias ----------------
// BK=32, 3 static LDS buffers (triple-unrolled K-loop), depth-2 prefetch, raw
// s_barrier + counted vmcnt(4) (loads never drain to 0 in the loop). K must be
// 1024 (both call sites). Staging slot (r, j) holds chunk j ^ ((r>>1)&3);
// readers use quad ^ ((l16>>1)&3) -> conflict-free. XCD-aware bijective block
// swizzle. mode 0: q (prescaled) / k [bh][n][64] dense 16B stores via LDS;
// vt [bh][64][n'] (sigma order) via LDS transpose. mode 1: fp32 out.
__global__ __launch_bounds__(256) void gemm_bt(const unsigned short* __restrict__ A,
                                               const unsigned short* __restrict__ Bt,
                                               const float* __restrict__ bias,
                                               int M, int N, int K, int mode,
                                               unsigned short* __restrict__ qo,
                                               unsigned short* __restrict__ ko,
                                               unsigned short* __restrict__ vto,
                                               float* __restrict__ outp) {
    // staging: 3 buffers x (A 4096 + B 4096) ushorts = 49152 B;
    // epilogues reuse [0,17408) ushorts as a 128x136 tile buffer.
    __shared__ unsigned short Sh[24576];
    const int tid = threadIdx.x;
    const int wave = tid >> 6, lane = tid & 63;
    const int quad = lane >> 4, l16 = lane & 15;
    // XCD-aware bijective swizzle: nwg = W*32 (768 or 256), both %8 == 0.
    const int W = gridDim.x;
    const int id = blockIdx.y * W + blockIdx.x;
    const int s = (id & 7) * (W << 2) + (id >> 3);
    const int bm = (s / W) * 128, bn = (s % W) * 128;
    const int wm = (wave >> 1) * 64, wn = (wave & 1) * 64;
    const int rsw = (quad ^ ((l16 >> 1) & 3)) << 3;   // reader chunk offset (ushorts)

    v4f acc[4][4];
#pragma unroll
    for (int i = 0; i < 4; i++)
#pragma unroll
        for (int j = 0; j < 4; j++) acc[i][j] = (v4f){0.f, 0.f, 0.f, 0.f};

#define GSTAGE(off, kk) do { \
    _Pragma("unroll") \
    for (int i_ = 0; i_ < 2; i_++) { \
        int c_ = i_ * 256 + tid; \
        int r_ = c_ >> 2; \
        int g_ = ((c_ & 3) ^ ((r_ >> 1) & 3)) << 3; \
        GLD16(&A[(bm + r_) * K + (kk) + g_], &Sh[(off) + (c_ << 3)]); \
        GLD16(&Bt[(bn + r_) * K + (kk) + g_], &Sh[(off) + 4096 + (c_ << 3)]); \
    } } while (0)

#define GCOMP(off) do { \
    v8s af_[4], bf_[4]; \
    _Pragma("unroll") \
    for (int mi_ = 0; mi_ < 4; mi_++) \
        af_[mi_] = *(const v8s*)&Sh[(off) + (wm + mi_ * 16 + l16) * 32 + rsw]; \
    _Pragma("unroll") \
    for (int ni_ = 0; ni_ < 4; ni_++) \
        bf_[ni_] = *(const v8s*)&Sh[(off) + 4096 + (wn + ni_ * 16 + l16) * 32 + rsw]; \
    _Pragma("unroll") \
    for (int mi_ = 0; mi_ < 4; mi_++) \
        _Pragma("unroll") \
        for (int ni_ = 0; ni_ < 4; ni_++) \
            acc[mi_][ni_] = __builtin_amdgcn_mfma_f32_16x16x32_bf16( \
                af_[mi_], bf_[ni_], acc[mi_][ni_], 0, 0, 0); \
    } while (0)

#define GSTEP(boff, soff, t) do { \
    asm volatile("s_waitcnt vmcnt(4)" ::: "memory"); \
    __builtin_amdgcn_s_barrier(); \
    __builtin_amdgcn_sched_barrier(0); \
    GSTAGE(soff, ((t) + 2) << 5); \
    GCOMP(boff); \
} while (0)

    // 32 K-steps (K=1024). Compute step t uses buf t%3; stage step s issued at
    // compute step s-2. Triple-unrolled -> all buffer offsets static.
    GSTAGE(0, 0);
    GSTAGE(8192, 32);
    for (int t = 0; t < 30; t += 3) {
        GSTEP(0,     16384, t);
        GSTEP(8192,  0,     t + 1);
        GSTEP(16384, 8192,  t + 2);
    }
    // step 30 (buf 0): stage31 still in flight
    asm volatile("s_waitcnt vmcnt(4)" ::: "memory");
    __builtin_amdgcn_s_barrier();
    __builtin_amdgcn_sched_barrier(0);
    GCOMP(0);
    // step 31 (buf 1): final drain
    asm volatile("s_waitcnt vmcnt(0)" ::: "memory");
    __builtin_amdgcn_s_barrier();
    __builtin_amdgcn_sched_barrier(0);
    GCOMP(8192);
#undef GSTEP
#undef GSTAGE
#undef GCOMP

    if (mode == 1) {
#pragma unroll
        for (int mi = 0; mi < 4; mi++)
#pragma unroll
            for (int ni = 0; ni < 4; ni++) {
                int col = bn + wn + ni * 16 + l16;
                float bv = bias[col];
                int row0 = bm + wm + mi * 16 + quad * 4;
#pragma unroll
                for (int r = 0; r < 4; r++)
                    outp[(row0 + r) * N + col] = acc[mi][ni][r] + bv;
            }
    } else if (bn < 2048) {
        // q or k: acc -> Sh row-major [r][c] pad 136 -> dense 16B row stores
        const int isq = (bn < 1024);
        unsigned short* dst = isq ? qo : ko;
        const float sc = isq ? QSCALE : 1.0f;
        __syncthreads();                          // staging reads done; Sh reusable
#pragma unroll
        for (int mi = 0; mi < 4; mi++)
#pragma unroll
            for (int ni = 0; ni < 4; ni++) {
                int c = wn + ni * 16 + l16;
                float bv = bias[bn + c];
                int r0 = wm + mi * 16 + quad * 4;
#pragma unroll
                for (int r = 0; r < 4; r++)
                    Sh[(r0 + r) * 136 + c] = f2bf_fast((acc[mi][ni][r] + bv) * sc);
            }
        __syncthreads();
        const int bb = bm >> 11, nb = bm & 2047;
#pragma unroll
        for (int j = 0; j < 8; j++) {
            int idx = j * 256 + tid;              // 2048 chunks: row=idx>>4, c8=idx&15
            int r = idx >> 4, c8 = idx & 15;
            int rem = (bn + c8 * 8) & 1023;
            int h = rem >> 6, dh = rem & 63;
            *(int4*)&dst[(((bb * 16 + h) << 11) + nb + r) * 64 + dh] =
                *(const int4*)&Sh[r * 136 + c8 * 8];
        }
    } else {
        // vt: transpose through LDS -> dense 16B stores. Sh[col_local*136 + row_local']
        // row_local' applies sigma within the wave's 64-key tile: each ushort4 pk is
        // one (m=mi, q=quad) group of 4 keys -> slot base 32*(mi>>1)+8*quad+4*(mi&1).
        __syncthreads();                          // staging reads done; Sh reusable
#pragma unroll
        for (int mi = 0; mi < 4; mi++)
#pragma unroll
            for (int ni = 0; ni < 4; ni++) {
                int col = bn + wn + ni * 16 + l16;
                float bv = bias[col];
                ushort4 pk;
                pk.x = f2bf_fast(acc[mi][ni][0] + bv);
                pk.y = f2bf_fast(acc[mi][ni][1] + bv);
                pk.z = f2bf_fast(acc[mi][ni][2] + bv);
                pk.w = f2bf_fast(acc[mi][ni][3] + bv);
                *(ushort4*)&Sh[(wn + ni * 16 + l16) * 136 +
                               wm + ((mi >> 1) * 32) + quad * 8 + ((mi & 1) * 4)] = pk;
            }
        __syncthreads();
        const int b = bm >> 11, n_base = bm & 2047;
#pragma unroll
        for (int j = 0; j < 8; j++) {
            int idx = j * 256 + tid;           // 2048 chunks of 8 ushorts
            int Lcol = idx >> 4, rc = idx & 15;
            int rem = (bn + Lcol) & 1023;
            int h = rem >> 6, dh = rem & 63;
            *(int4*)&vto[((((b * 16 + h) * 64 + dh) << 11) + n_base + rc * 8)] =
                *(const int4*)&Sh[Lcol * 136 + rc * 8];
        }
    }
}

// ---------------- flash attention: BK=64, 32 q-rows/wave, pipelined ----------------
// q (prescaled), k: [bh][2048][64]; vt: [bh][64][2048 sigma-slots]; o: bf16
// Phase t: WAITB -> STAGE(t+1) [top: full phase covers latency] ->
// EXPP(s[t-1]) || QK(K[t&1]) -> s[t] || PV(af, V[(t-1)&3]) -- independent
// chains interleaved by the scheduler. All 32 phases fully unrolled: K/V
// buffer offsets compile-time static (K[2], V[4] = 48KB LDS).
__global__ __launch_bounds__(256, 2) void attn(const unsigned short* __restrict__ q,
                                               const unsigned short* __restrict__ k,
                                               const unsigned short* __restrict__ vt,
                                               unsigned short* __restrict__ o) {
    __shared__ unsigned short KsF[2 * 4096];    // [key][d]   swizzled  (2 x 8192 B)
    __shared__ unsigned short VsF[4 * 4096];    // [d][slot]  swizzled  (4 x 8192 B)
    const int tid = threadIdx.x;
    const int wave = tid >> 6, lane = tid & 63;
    const int quad = lane >> 4, l16 = lane & 15;
    const int sw = l16 & 7;

    // XCD-aware swizzle: id in [0,512). Low 5 bits -> bh (8 XCDs x 4 bh each),
    // high bits -> q-block in [0,16). Each XCD sees 4 bh => K/V fits its L2.
    const int id = blockIdx.y * 16 + blockIdx.x;
    const int bh = (id & 7) * 4 + ((id >> 3) & 3);
    const int wq0 = (id >> 5) * 128 + wave * 32;
    const int rowg = bh * 2048 + wq0;

    // Q B-frags: group g covers q-rows wq0 + g*16 + l16, d = half*32 + quad*8..+7
    v8s qf[2][2];
#pragma unroll
    for (int g = 0; g < 2; g++)
#pragma unroll
        for (int half = 0; half < 2; half++)
            qf[g][half] = *(const v8s*)&q[(rowg + g * 16 + l16) * 64 + half * 32 + quad * 8];

    // register ones B-frag (bf16 1.0)
    v8s onef;
#pragma unroll
    for (int j = 0; j < 8; j++) onef[j] = (short)0x3F80;

    v4f oacc[2][4];
    v4f lacc[2];
#pragma unroll
    for (int g = 0; g < 2; g++) {
        lacc[g] = (v4f){0.f, 0.f, 0.f, 0.f};
#pragma unroll
        for (int dt = 0; dt < 4; dt++) oacc[g][dt] = (v4f){0.f, 0.f, 0.f, 0.f};
    }

    const unsigned short* kbase = k + (((long)bh << 11) * 64);
    const unsigned short* vbase = vt + (((long)bh * 64) << 11);

#define STAGE(ko, vo, n0s) do { \
    _Pragma("unroll") \
    for (int i_ = 0; i_ < 2; i_++) { \
        int c_ = i_ * 256 + tid; \
        int r_ = c_ >> 3; \
        int chs_ = ((c_ & 7) ^ (r_ & 7)) << 3; \
        GLD16(&kbase[((n0s) + r_) * 64 + chs_], &KsF[(ko) + (c_ << 3)]); \
        GLD16(&vbase[(r_ << 11) + (n0s) + chs_], &VsF[(vo) + (c_ << 3)]); \
    } } while (0)

#define WAITB() do { asm volatile("s_waitcnt vmcnt(0)" ::: "memory"); \
    __builtin_amdgcn_s_barrier(); __builtin_amdgcn_sched_barrier(0); } while (0)

    // QK: S^T for both q-groups; s[g][ni][r] = S[key=ni*16+quad*4+r][wq0+g*16+l16]
    auto QK = [&](const unsigned short* Kc, v4f (&sr)[2][4]) {
#pragma unroll
        for (int ni = 0; ni < 4; ni++) {
            int rowk = (ni * 16 + l16) * 64;
            v8s kf0 = *(const v8s*)&Kc[rowk + ((quad ^ sw) << 3)];
            v8s kf1 = *(const v8s*)&Kc[rowk + (((4 + quad) ^ sw) << 3)];
#pragma unroll
            for (int g = 0; g < 2; g++) {
                v4f z = (v4f){0.f, 0.f, 0.f, 0.f};
                z = __builtin_amdgcn_mfma_f32_16x16x32_bf16(kf0, qf[g][0], z, 0, 0, 0);
                z = __builtin_amdgcn_mfma_f32_16x16x32_bf16(kf1, qf[g][1], z, 0, 0, 0);
                sr[g][ni] = z;
            }
        }
    };
    // EXPP: exp2 + in-register kappa pack -> A-frags
    auto EXPP = [&](v4f (&sr)[2][4], v8s (&afr)[2][2]) {
#pragma unroll
        for (int g = 0; g < 2; g++)
#pragma unroll
            for (int t = 0; t < 2; t++) {
                v4u w;
                w[0] = pack_bf16(EXP2(sr[g][2 * t][0]),     EXP2(sr[g][2 * t][1]));
                w[1] = pack_bf16(EXP2(sr[g][2 * t][2]),     EXP2(sr[g][2 * t][3]));
                w[2] = pack_bf16(EXP2(sr[g][2 * t + 1][0]), EXP2(sr[g][2 * t + 1][1]));
                w[3] = pack_bf16(EXP2(sr[g][2 * t + 1][2]), EXP2(sr[g][2 * t + 1][3]));
                union { v4u u; v8s s8; } cv;
                cv.u = w;
                afr[g][t] = cv.s8;
            }
    };
    // PV: O += P V (sigma-slotted V: one b128/frag, conflict-free); l += P.1
    auto PV = [&](v8s (&afr)[2][2], const unsigned short* Vc) {
#pragma unroll
        for (int dt = 0; dt < 4; dt++) {
            int rowv = (dt * 16 + l16) * 64;
            v8s vf0 = *(const v8s*)&Vc[rowv + ((quad ^ sw) << 3)];
            v8s vf1 = *(const v8s*)&Vc[rowv + (((4 + quad) ^ sw) << 3)];
#pragma unroll
            for (int g = 0; g < 2; g++) {
                oacc[g][dt] = __builtin_amdgcn_mfma_f32_16x16x32_bf16(afr[g][0], vf0, oacc[g][dt], 0, 0, 0);
                oacc[g][dt] = __builtin_amdgcn_mfma_f32_16x16x32_bf16(afr[g][1], vf1, oacc[g][dt], 0, 0, 0);
            }
        }
#pragma unroll
        for (int g = 0; g < 2; g++) {
            lacc[g] = __builtin_amdgcn_mfma_f32_16x16x32_bf16(afr[g][0], onef, lacc[g], 0, 0, 0);
            lacc[g] = __builtin_amdgcn_mfma_f32_16x16x32_bf16(afr[g][1], onef, lacc[g], 0, 0, 0);
        }
    };

    v4f sreg[2][2][4];     // [tile parity][group][ni] -- statically indexed
    v8s af[2][2];

    // phase T (fully unrolled, T literal): finish tile T-1, QK tile T, stage T+1
#define PHASE(T) do { \
    WAITB(); \
    if ((T) < 31) STAGE(((((T) + 1) & 1) * 4096), ((((T) + 1) & 3) * 4096), (((T) + 1) * 64)); \
    __builtin_amdgcn_s_setprio(1); \
    EXPP(sreg[((T) + 1) & 1], af); \
    QK(KsF + ((T) & 1) * 4096, sreg[(T) & 1]); \
    PV(af, VsF + ((((T) + 3) & 3) * 4096)); \
    __builtin_amdgcn_s_setprio(0); \
} while (0)

    // prologue: stage tile0; phase 0 = {stage tile1, QK tile0}
    STAGE(0, 0, 0);
    WAITB();
    STAGE(4096, 4096, 64);
    QK(KsF, sreg[0]);

    PHASE(1);  PHASE(2);  PHASE(3);  PHASE(4);  PHASE(5);  PHASE(6);
    PHASE(7);  PHASE(8);  PHASE(9);  PHASE(10); PHASE(11); PHASE(12);
    PHASE(13); PHASE(14); PHASE(15); PHASE(16); PHASE(17); PHASE(18);
    PHASE(19); PHASE(20); PHASE(21); PHASE(22); PHASE(23); PHASE(24);
    PHASE(25); PHASE(26); PHASE(27); PHASE(28); PHASE(29); PHASE(30);
    PHASE(31);
    // tail: finish tile 31
    __builtin_amdgcn_s_setprio(1);
    EXPP(sreg[1], af);
    PV(af, VsF + 3 * 4096);
    __builtin_amdgcn_s_setprio(0);
#undef PHASE
#undef STAGE
#undef WAITB

    const int b = bh >> 4, h = bh & 15;
#pragma unroll
    for (int g = 0; g < 2; g++)
#pragma unroll
        for (int r = 0; r < 4; r++) {
            float linv = 1.0f / lacc[g][r];   // l present in every lane (broadcast ones B)
            int n = wq0 + g * 16 + quad * 4 + r;
#pragma unroll
            for (int dt = 0; dt < 4; dt++)
                o[(b * 2048 + n) * 1024 + h * 64 + dt * 16 + l16] =
                    f2bf_fast(oacc[g][dt][r] * linv);
        }
}

extern "C" void kernel_launch(void* const* d_in, const int* in_sizes, int n_in,
                              void* d_out, int out_size, void* d_ws, size_t ws_size,
                              hipStream_t stream) {
    const float* x      = (const float*)d_in[0];   // [2,2048,1024]
    const float* w_qkv  = (const float*)d_in[1];   // [1024,3072]
    const float* b_qkv  = (const float*)d_in[2];   // [3072]
    const float* w_proj = (const float*)d_in[3];   // [1024,1024]
    const float* b_proj = (const float*)d_in[4];   // [1024]
    float* outp = (float*)d_out;                   // [2,2048,1024] fp32

    unsigned short* ws     = (unsigned short*)d_ws;
    unsigned short* xb     = ws;                   // 4096*1024
    unsigned short* wqkvt  = ws + 4194304;         // 3072*1024
    unsigned short* wprojt = wqkvt + 3145728;      // 1024*1024
    unsigned short* qws    = wprojt + 1048576;     // 32*2048*64
    unsigned short* kws    = qws + 4194304;
    unsigned short* vtws   = kws + 4194304;
    unsigned short* ows    = xb;                   // alias: xb dead after QKV GEMM

    prep<<<8192, 256, 0, stream>>>(x, xb, w_qkv, wqkvt, w_proj, wprojt);
    gemm_bt<<<dim3(24, 32), 256, 0, stream>>>(xb, wqkvt, b_qkv, 4096, 3072, 1024, 0,
                                              qws, kws, vtws, nullptr);
    attn<<<dim3(16, 32), 256, 0, stream>>>(qws, kws, vtws, ows);
    gemm_bt<<<dim3(8, 32), 256, 0, stream>>>(ows, wprojt, b_proj, 4096, 1024, 1024, 1,
                                             nullptr, nullptr, nullptr, outp);
}